// Round 2
// baseline (465.928 us; speedup 1.0000x reference)
//
#include <hip/hip_runtime.h>

typedef __attribute__((ext_vector_type(4))) int i32x4;

#define AS1 __attribute__((address_space(1)))
#define AS3 __attribute__((address_space(3)))

static constexpr int  S_LEN = 2048, DIN = 4096, DOUT = 4096, NBATCH = 4;
static constexpr long XTOT = (long)NBATCH * S_LEN * DIN;  // 2^25 elements
static constexpr long WTOT = (long)DOUT * DIN;            // 2^24 elements
static constexpr float QMAXF = 127.0f;
static constexpr float EPSF  = 1e-8f;

// ---------------------------------------------------------------------------
// Kernel 1: per-batch amax(|x|) (y=0..3) and per-tensor amax(|w|) (y=4).
// float4 loads, wave shuffle-reduce, one device-scope atomicMax per block
// (uint compare == float compare for non-negative values).
// ---------------------------------------------------------------------------
__global__ void amax_k(const float* __restrict__ x, const float* __restrict__ w,
                       float* __restrict__ amax) {
  int y = blockIdx.y;
  const float4* src;
  long n4;
  if (y < NBATCH) { src = (const float4*)(x + (long)y * S_LEN * DIN); n4 = (long)S_LEN * DIN / 4; }
  else            { src = (const float4*)w; n4 = WTOT / 4; }
  float m = 0.f;
  for (long i = (long)blockIdx.x * blockDim.x + threadIdx.x; i < n4;
       i += (long)gridDim.x * blockDim.x) {
    float4 v = src[i];
    m = fmaxf(m, fmaxf(fmaxf(fabsf(v.x), fabsf(v.y)), fmaxf(fabsf(v.z), fabsf(v.w))));
  }
  for (int off = 32; off; off >>= 1) m = fmaxf(m, __shfl_xor(m, off, 64));
  __shared__ float sm[4];
  if ((threadIdx.x & 63) == 0) sm[threadIdx.x >> 6] = m;
  __syncthreads();
  if (threadIdx.x == 0) {
    m = fmaxf(fmaxf(sm[0], sm[1]), fmaxf(sm[2], sm[3]));
    atomicMax((unsigned int*)&amax[y], __float_as_uint(m));
  }
}

// ---------------------------------------------------------------------------
// Kernel 2: quantize x and w to int8, 16 elements/thread, 16B stores.
// Bit-matching grid vs reference: scale = fmaxf(amax,EPS)/127, IEEE fp32
// divide, rintf (round-half-even == jnp.round), clamp to +-127 AFTER round.
// ---------------------------------------------------------------------------
__global__ void quant_k(const float* __restrict__ x, const float* __restrict__ w,
                        const float* __restrict__ amax,
                        char* __restrict__ qx, char* __restrict__ qw) {
  long idx = ((long)blockIdx.x * blockDim.x + threadIdx.x) * 16;
  const float* src;
  char* dst;
  float scale;
  if (idx < XTOT) {
    int b = (int)(idx >> 23);           // per-batch elements = 2048*4096 = 2^23
    scale = fmaxf(amax[b], EPSF) / QMAXF;
    src = x + idx;
    dst = qx + idx;
  } else {
    long j = idx - XTOT;
    scale = fmaxf(amax[4], EPSF) / QMAXF;
    src = w + j;
    dst = qw + j;
  }
  int words[4];
#pragma unroll
  for (int g = 0; g < 4; ++g) {
    float4 v = ((const float4*)src)[g];
    float r0 = fminf(fmaxf(rintf(v.x / scale), -QMAXF), QMAXF);
    float r1 = fminf(fmaxf(rintf(v.y / scale), -QMAXF), QMAXF);
    float r2 = fminf(fmaxf(rintf(v.z / scale), -QMAXF), QMAXF);
    float r3 = fminf(fmaxf(rintf(v.w / scale), -QMAXF), QMAXF);
    words[g] = ((int)r0 & 255) | (((int)r1 & 255) << 8) |
               (((int)r2 & 255) << 16) | ((int)r3 << 24);
  }
  *(i32x4*)dst = *(const i32x4*)words;
}

// ---------------------------------------------------------------------------
// Kernel 3: i8 NT GEMM  out[M=8192][N=4096] = sx*sw * (qx @ qw^T) + bias.
// m97 structure: 128x128 tile, 4 waves (2x2, 64x64/wave), BK=64,
// mfma_i32_16x16x64_i8 (16 MFMA : 8 ds_read_b128 per K-step per wave).
// global_load_lds width=16 staging, LINEAR LDS dest + inverse-XOR on the
// GLOBAL source + matching XOR on ds_read (rule #21) -> 2-way banks (free).
// XCD-aware block swizzle (nwg=2048 % 8 == 0 -> simple form bijective).
// ---------------------------------------------------------------------------
__global__ __launch_bounds__(256) void gemm_k(
    const char* __restrict__ qx, const char* __restrict__ qw,
    const float* __restrict__ amax, const float* __restrict__ bias,
    float* __restrict__ out) {
  constexpr int BM = 128, BN = 128, BK = 64, K = 4096, N = 4096;
  __shared__ __align__(16) char As[BM * BK];  // 8 KiB
  __shared__ __align__(16) char Bs[BN * BK];  // 8 KiB

  int cpx = gridDim.x >> 3;
  int sw  = (blockIdx.x & 7) * cpx + (blockIdx.x >> 3);
  int tm = sw >> 5;   // 64 row tiles
  int tn = sw & 31;   // 32 col tiles
  long brow = (long)tm * BM;
  long bcol = (long)tn * BN;

  int tid = threadIdx.x;
  int lane = tid & 63, wid = tid >> 6;
  int wr = wid >> 1, wc = wid & 1;

  // staging: thread t loads 16B; tile row = t>>2, physical unit = t&3,
  // logical (global) unit = phys ^ ((row>>1)&3)
  int r0 = tid >> 2;
  int p  = tid & 3;
  int lu = p ^ ((r0 >> 1) & 3);
  const char* gA0 = qx + (brow + r0) * (long)K + lu * 16;
  const char* gA1 = gA0 + 64 * (long)K;
  const char* gB0 = qw + (bcol + r0) * (long)K + lu * 16;
  const char* gB1 = gB0 + 64 * (long)K;

  // per-lane fragment read offsets (swizzled): row = f*16 + (lane&15),
  // logical K-unit = lane>>4, physical = logical ^ ((row>>1)&3)
  int offA[4], offB[4];
#pragma unroll
  for (int f = 0; f < 4; ++f) {
    int rowa = wr * 64 + f * 16 + (lane & 15);
    offA[f] = rowa * 64 + (((lane >> 4) ^ ((rowa >> 1) & 3)) * 16);
    int rowb = wc * 64 + f * 16 + (lane & 15);
    offB[f] = rowb * 64 + (((lane >> 4) ^ ((rowb >> 1) & 3)) * 16);
  }

  i32x4 acc[4][4];
#pragma unroll
  for (int i = 0; i < 4; ++i)
#pragma unroll
    for (int j = 0; j < 4; ++j) acc[i][j] = 0;

  for (int kt = 0; kt < K / BK; ++kt) {
    long ko = (long)kt * BK;
    __builtin_amdgcn_global_load_lds((const AS1 void*)(gA0 + ko),
                                     (AS3 void*)(As + wid * 1024), 16, 0, 0);
    __builtin_amdgcn_global_load_lds((const AS1 void*)(gA1 + ko),
                                     (AS3 void*)(As + 4096 + wid * 1024), 16, 0, 0);
    __builtin_amdgcn_global_load_lds((const AS1 void*)(gB0 + ko),
                                     (AS3 void*)(Bs + wid * 1024), 16, 0, 0);
    __builtin_amdgcn_global_load_lds((const AS1 void*)(gB1 + ko),
                                     (AS3 void*)(Bs + 4096 + wid * 1024), 16, 0, 0);
    asm volatile("s_waitcnt vmcnt(0)" ::: "memory");
    __syncthreads();

    i32x4 a[4], b[4];
#pragma unroll
    for (int f = 0; f < 4; ++f) a[f] = *(const i32x4*)(As + offA[f]);
#pragma unroll
    for (int f = 0; f < 4; ++f) b[f] = *(const i32x4*)(Bs + offB[f]);
#pragma unroll
    for (int m = 0; m < 4; ++m)
#pragma unroll
      for (int n = 0; n < 4; ++n)
        acc[m][n] = __builtin_amdgcn_mfma_i32_16x16x64_i8(a[m], b[n], acc[m][n], 0, 0, 0);

    __syncthreads();
  }

  // epilogue: out = sx*sw*acc + bias  (C/D: col=lane&15, row=(lane>>4)*4+reg)
  float ax = amax[(int)(brow >> 11)];   // 2048 rows per batch
  float aw = amax[4];
  float scale = (fmaxf(ax, EPSF) / QMAXF) * (fmaxf(aw, EPSF) / QMAXF);
#pragma unroll
  for (int fn = 0; fn < 4; ++fn) {
    int col = (int)bcol + wc * 64 + fn * 16 + (lane & 15);
    float bv = bias[col];
#pragma unroll
    for (int fm = 0; fm < 4; ++fm) {
      long rbase = brow + wr * 64 + fm * 16 + ((lane >> 4) * 4);
#pragma unroll
      for (int r = 0; r < 4; ++r) {
        out[(rbase + r) * N + col] = scale * (float)acc[fm][fn][r] + bv;
      }
    }
  }
}

// ---------------------------------------------------------------------------
extern "C" void kernel_launch(void* const* d_in, const int* in_sizes, int n_in,
                              void* d_out, int out_size, void* d_ws, size_t ws_size,
                              hipStream_t stream) {
  const float* x    = (const float*)d_in[0];
  const float* w    = (const float*)d_in[1];
  const float* bias = (const float*)d_in[2];
  float* out = (float*)d_out;

  float* amax = (float*)d_ws;              // 5 floats used
  char* qx = (char*)d_ws + 256;            // 2^25 bytes
  char* qw = qx + XTOT;                    // 2^24 bytes
  if (ws_size < (size_t)(256 + XTOT + WTOT)) return;  // ws too small: fail loudly

  hipMemsetAsync(d_ws, 0, 32, stream);     // zero amax slots (ws re-poisoned 0xAA)

  amax_k<<<dim3(256, 5), 256, 0, stream>>>(x, w, amax);

  long total = XTOT + WTOT;                          // 50331648 elems
  int qblocks = (int)(total / 16 / 256);             // 12288
  quant_k<<<qblocks, 256, 0, stream>>>(x, w, amax, qx, qw);

  gemm_k<<<(8192 / 128) * (4096 / 128), 256, 0, stream>>>(qx, qw, amax, bias, out);
}

// Round 3
// 429.020 us; speedup vs baseline: 1.0860x; 1.0860x over previous
//
#include <hip/hip_runtime.h>

typedef __attribute__((ext_vector_type(4))) int i32x4;

#define AS1 __attribute__((address_space(1)))
#define AS3 __attribute__((address_space(3)))

static constexpr int  S_LEN = 2048, DIN = 4096, DOUT = 4096, NBATCH = 4;
static constexpr long XTOT = (long)NBATCH * S_LEN * DIN;  // 2^25
static constexpr long WTOT = (long)DOUT * DIN;            // 2^24
static constexpr float QMAXF = 127.0f;
static constexpr float EPSF  = 1e-8f;

// ---------------------------------------------------------------------------
// Kernel 1: amax. Flat 3072-block grid: blocks [0,2048) -> x batches (512
// blocks each), [2048,3072) -> w. Uniform 16 unrolled float4 loads/thread.
// ---------------------------------------------------------------------------
__global__ __launch_bounds__(256) void amax_k(const float* __restrict__ x,
                                              const float* __restrict__ w,
                                              float* __restrict__ amax) {
  int bid = blockIdx.x;
  float m = 0.f;
  int slot;
  if (bid < 2048) {
    slot = bid >> 9;
    const float4* s = (const float4*)(x + ((long)slot << 23));
    long i = ((long)(bid & 511) << 8) + threadIdx.x;
#pragma unroll
    for (int it = 0; it < 16; ++it) {
      float4 v = s[i + (long)it * (512 * 256)];
      m = fmaxf(m, fmaxf(fmaxf(fabsf(v.x), fabsf(v.y)), fmaxf(fabsf(v.z), fabsf(v.w))));
    }
  } else {
    slot = 4;
    const float4* s = (const float4*)w;
    long i = ((long)(bid - 2048) << 8) + threadIdx.x;
#pragma unroll
    for (int it = 0; it < 16; ++it) {
      float4 v = s[i + (long)it * (1024 * 256)];
      m = fmaxf(m, fmaxf(fmaxf(fabsf(v.x), fabsf(v.y)), fmaxf(fabsf(v.z), fabsf(v.w))));
    }
  }
  for (int off = 32; off; off >>= 1) m = fmaxf(m, __shfl_xor(m, off, 64));
  __shared__ float sm[4];
  if ((threadIdx.x & 63) == 0) sm[threadIdx.x >> 6] = m;
  __syncthreads();
  if (threadIdx.x == 0) {
    m = fmaxf(fmaxf(sm[0], sm[1]), fmaxf(sm[2], sm[3]));
    atomicMax((unsigned int*)&amax[slot], __float_as_uint(m));
  }
}

// ---------------------------------------------------------------------------
// Kernel 2: quantize x and w to int8 (UNCHANGED numerics: IEEE divide, rintf).
// ---------------------------------------------------------------------------
__global__ __launch_bounds__(256) void quant_k(const float* __restrict__ x,
                                               const float* __restrict__ w,
                                               const float* __restrict__ amax,
                                               char* __restrict__ qx, char* __restrict__ qw) {
  long idx = ((long)blockIdx.x * blockDim.x + threadIdx.x) * 16;
  const float* src;
  char* dst;
  float scale;
  if (idx < XTOT) {
    int b = (int)(idx >> 23);
    scale = fmaxf(amax[b], EPSF) / QMAXF;
    src = x + idx;
    dst = qx + idx;
  } else {
    long j = idx - XTOT;
    scale = fmaxf(amax[4], EPSF) / QMAXF;
    src = w + j;
    dst = qw + j;
  }
  int words[4];
#pragma unroll
  for (int g = 0; g < 4; ++g) {
    float4 v = ((const float4*)src)[g];
    float r0 = fminf(fmaxf(rintf(v.x / scale), -QMAXF), QMAXF);
    float r1 = fminf(fmaxf(rintf(v.y / scale), -QMAXF), QMAXF);
    float r2 = fminf(fmaxf(rintf(v.z / scale), -QMAXF), QMAXF);
    float r3 = fminf(fmaxf(rintf(v.w / scale), -QMAXF), QMAXF);
    words[g] = ((int)r0 & 255) | (((int)r1 & 255) << 8) |
               (((int)r2 & 255) << 16) | ((int)r3 << 24);
  }
  *(i32x4*)dst = *(const i32x4*)words;
}

// ---------------------------------------------------------------------------
// Kernel 3: i8 NT GEMM, 256x256 tile, 8-phase counted-vmcnt schedule.
// 8 waves (2M x 4N), wave tile 128x64. K-tile = 128 i8 (128 B rows, byte-
// identical to the bf16 template's BK=64). LDS 128 KiB: A[2][256][128] @0,
// B @65536. Swizzle: 16B-unit ^= (row>>1)&7, applied on pre-swizzled global
// source (linear LDS dest, rule #21) and on ds_read addresses.
// Per K-tile: 4 phases (A0B0)(A0B1)(A1B1)(A1B0); B0 stays in regs for q3.
// Stages: q0 A1(t+1), q1 B1(t+1), q3 A0(t+2)+B0(t+2); vmcnt(4) at q3 only
// (never 0 in steady state), drains at t=NT-2.
// ---------------------------------------------------------------------------
__device__ __forceinline__ void load_half_a(i32x4 a[4][2], const char* p, int u0, int u1) {
#pragma unroll
  for (int f = 0; f < 4; ++f) {
    a[f][0] = *(const i32x4*)(p + f * 2048 + u0);
    a[f][1] = *(const i32x4*)(p + f * 2048 + u1);
  }
}
__device__ __forceinline__ void load_half_b(i32x4 b[2][2], const char* p, int u0, int u1) {
#pragma unroll
  for (int g = 0; g < 2; ++g) {
    b[g][0] = *(const i32x4*)(p + g * 2048 + u0);
    b[g][1] = *(const i32x4*)(p + g * 2048 + u1);
  }
}
template <int QA, int QB>
__device__ __forceinline__ void do_mfma(i32x4 acc[8][4], const i32x4 a[4][2],
                                        const i32x4 b[2][2]) {
#pragma unroll
  for (int f = 0; f < 4; ++f)
#pragma unroll
    for (int g = 0; g < 2; ++g) {
      i32x4 c = acc[QA * 4 + f][QB * 2 + g];
      c = __builtin_amdgcn_mfma_i32_16x16x64_i8(a[f][0], b[g][0], c, 0, 0, 0);
      c = __builtin_amdgcn_mfma_i32_16x16x64_i8(a[f][1], b[g][1], c, 0, 0, 0);
      acc[QA * 4 + f][QB * 2 + g] = c;
    }
}
__device__ __forceinline__ void stage2(const char* g0, long K, char* ld) {
  __builtin_amdgcn_global_load_lds((const AS1 void*)g0, (AS3 void*)ld, 16, 0, 0);
  __builtin_amdgcn_global_load_lds((const AS1 void*)(g0 + 64 * K), (AS3 void*)(ld + 8192), 16, 0, 0);
}

__global__ __launch_bounds__(512, 2) void gemm_k(
    const char* __restrict__ qx, const char* __restrict__ qw,
    const float* __restrict__ amax, const float* __restrict__ bias,
    float* __restrict__ out) {
  constexpr int K = 4096, N = 4096, NT = 32;  // NT = K / 128
  __shared__ __align__(16) char lds[131072];
  char* ldsA = lds;
  char* ldsB = lds + 65536;

  // XCD swizzle (512 blocks, %8==0 -> bijective). 32 M-tiles x 16 N-tiles.
  int cpx = (int)gridDim.x >> 3;
  int sw  = ((int)blockIdx.x & 7) * cpx + ((int)blockIdx.x >> 3);
  int tm = sw >> 4, tn = sw & 15;
  long brow = (long)tm * 256, bcol = (long)tn * 256;

  int tid = threadIdx.x;
  int l = tid & 63, wid = tid >> 6;
  int wr = wid >> 2, wc = wid & 3;  // 2 x 4 waves

  // ds-read per-lane offsets: unit = (ku [kk*4 + l>>4]) ^ ((row>>1)&7);
  // row = base16 + (l&15) with base16 % 16 == 0 -> swz term = (l>>1)&7.
  int sl = (l >> 1) & 7;
  int u0 = (((l >> 4) ^ sl)) << 4;
  int u1 = ((((l >> 4) | 4) ^ sl)) << 4;
  int rA = (wr * 128 + (l & 15)) * 128;
  int rB = (wc * 64 + (l & 15)) * 128;

  // staging: thread covers row sr0 (call0) / sr0+64 (call1), 16B unit
  // pre-swizzled in the global source ((row>>1)&7 invariant under +64).
  int sr0 = tid >> 3;
  int lu16 = ((tid & 7) ^ ((sr0 >> 1) & 7)) << 4;
  const char* gA = qx + (brow + sr0) * (long)K + lu16;
  const char* gB = qw + (bcol + sr0) * (long)K + lu16;

  i32x4 acc[8][4];
#pragma unroll
  for (int i = 0; i < 8; ++i)
#pragma unroll
    for (int j = 0; j < 4; ++j) acc[i][j] = 0;
  i32x4 a[4][2], b0[2][2], b1[2][2];

  // ---- prologue: A0(0) B0(0) A1(0) B1(0) A0(1) B0(1); allow last 2 stages
  // (4 loads) outstanding.
  stage2(gA, K, ldsA + tid * 16);
  stage2(gB, K, ldsB + tid * 16);
  stage2(gA + 128 * (long)K, K, ldsA + 16384 + tid * 16);
  stage2(gB + 128 * (long)K, K, ldsB + 16384 + tid * 16);
  stage2(gA + 128, K, ldsA + 32768 + tid * 16);
  stage2(gB + 128, K, ldsB + 32768 + tid * 16);
  asm volatile("s_waitcnt vmcnt(4)" ::: "memory");
  __builtin_amdgcn_s_barrier();

  for (int t = 0; t < NT; ++t) {
    int d = t & 1;
    const char* cA = ldsA + d * 32768;
    const char* cB = ldsB + d * 32768;
    // ---------- q0: (A0,B0); stage A1(t+1)
    load_half_a(a, cA + rA, u0, u1);
    load_half_b(b0, cB + rB, u0, u1);
    if (t + 1 < NT)
      stage2(gA + 128 * (long)K + (t + 1) * 128, K,
             ldsA + ((t + 1) & 1) * 32768 + 16384 + tid * 16);
    __builtin_amdgcn_s_barrier();
    asm volatile("s_waitcnt lgkmcnt(0)" ::: "memory");
    __builtin_amdgcn_s_setprio(1);
    do_mfma<0, 0>(acc, a, b0);
    __builtin_amdgcn_s_setprio(0);
    __builtin_amdgcn_s_barrier();
    // ---------- q1: (A0,B1); stage B1(t+1)
    load_half_b(b1, cB + rB + 4096, u0, u1);
    if (t + 1 < NT)
      stage2(gB + 128 * (long)K + (t + 1) * 128, K,
             ldsB + ((t + 1) & 1) * 32768 + 16384 + tid * 16);
    __builtin_amdgcn_s_barrier();
    asm volatile("s_waitcnt lgkmcnt(0)" ::: "memory");
    __builtin_amdgcn_s_setprio(1);
    do_mfma<0, 1>(acc, a, b1);
    __builtin_amdgcn_s_setprio(0);
    __builtin_amdgcn_s_barrier();
    // ---------- q2: (A1,B1); no stage
    load_half_a(a, cA + rA + 8192, u0, u1);
    __builtin_amdgcn_s_barrier();
    asm volatile("s_waitcnt lgkmcnt(0)" ::: "memory");
    __builtin_amdgcn_s_setprio(1);
    do_mfma<1, 1>(acc, a, b1);
    __builtin_amdgcn_s_setprio(0);
    __builtin_amdgcn_s_barrier();
    // ---------- q3: (A1,B0) from regs; stage A0(t+2), B0(t+2); vmcnt
    if (t + 2 < NT) {
      stage2(gA + (t + 2) * 128, K, ldsA + d * 32768 + tid * 16);
      stage2(gB + (t + 2) * 128, K, ldsB + d * 32768 + tid * 16);
    }
    __builtin_amdgcn_s_barrier();
    __builtin_amdgcn_s_setprio(1);
    do_mfma<1, 0>(acc, a, b0);
    __builtin_amdgcn_s_setprio(0);
    if (t < NT - 2) asm volatile("s_waitcnt vmcnt(4)" ::: "memory");
    else            asm volatile("s_waitcnt vmcnt(0)" ::: "memory");
    __builtin_amdgcn_s_barrier();
  }

  // ---- epilogue: out = sx*sw*acc + bias (C/D: col=lane&15, row=(l>>4)*4+r)
  float ax = amax[(int)(brow >> 11)];
  float aw = amax[4];
  float scale = (fmaxf(ax, EPSF) / QMAXF) * (fmaxf(aw, EPSF) / QMAXF);
#pragma unroll
  for (int fb = 0; fb < 4; ++fb) {
    int col = (int)bcol + wc * 64 + fb * 16 + (l & 15);
    float bv = bias[col];
#pragma unroll
    for (int fa = 0; fa < 8; ++fa) {
      long r0 = brow + wr * 128 + fa * 16 + ((l >> 4) * 4);
#pragma unroll
      for (int r = 0; r < 4; ++r)
        out[(r0 + r) * N + col] = scale * (float)acc[fa][fb][r] + bv;
    }
  }
}

// ---------------------------------------------------------------------------
extern "C" void kernel_launch(void* const* d_in, const int* in_sizes, int n_in,
                              void* d_out, int out_size, void* d_ws, size_t ws_size,
                              hipStream_t stream) {
  const float* x    = (const float*)d_in[0];
  const float* w    = (const float*)d_in[1];
  const float* bias = (const float*)d_in[2];
  float* out = (float*)d_out;

  float* amax = (float*)d_ws;
  char* qx = (char*)d_ws + 256;
  char* qw = qx + XTOT;
  if (ws_size < (size_t)(256 + XTOT + WTOT)) return;

  hipMemsetAsync(d_ws, 0, 32, stream);

  amax_k<<<3072, 256, 0, stream>>>(x, w, amax);

  long total = XTOT + WTOT;
  int qblocks = (int)(total / 16 / 256);  // 12288
  quant_k<<<qblocks, 256, 0, stream>>>(x, w, amax, qx, qw);

  gemm_k<<<512, 512, 0, stream>>>(qx, qw, amax, bias, out);
}

// Round 7
// 424.402 us; speedup vs baseline: 1.0978x; 1.0109x over previous
//
#include <hip/hip_runtime.h>

typedef __attribute__((ext_vector_type(4))) int i32x4;

#define AS1 __attribute__((address_space(1)))
#define AS3 __attribute__((address_space(3)))

static constexpr int  S_LEN = 2048, DIN = 4096, DOUT = 4096, NBATCH = 4;
static constexpr long XTOT = (long)NBATCH * S_LEN * DIN;  // 2^25
static constexpr long WTOT = (long)DOUT * DIN;            // 2^24
static constexpr float QMAXF = 127.0f;
static constexpr float EPSF  = 1e-8f;

// ---------------------------------------------------------------------------
// Kernel 1: amax. Blocks [0,2048) -> x batches (512 each), [2048,3072) -> w.
// ---------------------------------------------------------------------------
__global__ __launch_bounds__(256) void amax_k(const float* __restrict__ x,
                                              const float* __restrict__ w,
                                              float* __restrict__ amax) {
  int bid = blockIdx.x;
  float m = 0.f;
  int slot;
  if (bid < 2048) {
    slot = bid >> 9;
    const float4* s = (const float4*)(x + ((long)slot << 23));
    long i = ((long)(bid & 511) << 8) + threadIdx.x;
#pragma unroll
    for (int it = 0; it < 16; ++it) {
      float4 v = s[i + (long)it * (512 * 256)];
      m = fmaxf(m, fmaxf(fmaxf(fabsf(v.x), fabsf(v.y)), fmaxf(fabsf(v.z), fabsf(v.w))));
    }
  } else {
    slot = 4;
    const float4* s = (const float4*)w;
    long i = ((long)(bid - 2048) << 8) + threadIdx.x;
#pragma unroll
    for (int it = 0; it < 16; ++it) {
      float4 v = s[i + (long)it * (1024 * 256)];
      m = fmaxf(m, fmaxf(fmaxf(fabsf(v.x), fabsf(v.y)), fmaxf(fabsf(v.z), fabsf(v.w))));
    }
  }
  for (int off = 32; off; off >>= 1) m = fmaxf(m, __shfl_xor(m, off, 64));
  __shared__ float sm[4];
  if ((threadIdx.x & 63) == 0) sm[threadIdx.x >> 6] = m;
  __syncthreads();
  if (threadIdx.x == 0) {
    m = fmaxf(fmaxf(sm[0], sm[1]), fmaxf(sm[2], sm[3]));
    atomicMax((unsigned int*)&amax[slot], __float_as_uint(m));
  }
}

// ---------------------------------------------------------------------------
// Kernel 2: quantize x and w to int8 (UNCHANGED numerics: IEEE divide, rintf).
// ---------------------------------------------------------------------------
__global__ __launch_bounds__(256) void quant_k(const float* __restrict__ x,
                                               const float* __restrict__ w,
                                               const float* __restrict__ amax,
                                               char* __restrict__ qx, char* __restrict__ qw) {
  long idx = ((long)blockIdx.x * blockDim.x + threadIdx.x) * 16;
  const float* src;
  char* dst;
  float scale;
  if (idx < XTOT) {
    int b = (int)(idx >> 23);
    scale = fmaxf(amax[b], EPSF) / QMAXF;
    src = x + idx;
    dst = qx + idx;
  } else {
    long j = idx - XTOT;
    scale = fmaxf(amax[4], EPSF) / QMAXF;
    src = w + j;
    dst = qw + j;
  }
  int words[4];
#pragma unroll
  for (int g = 0; g < 4; ++g) {
    float4 v = ((const float4*)src)[g];
    float r0 = fminf(fmaxf(rintf(v.x / scale), -QMAXF), QMAXF);
    float r1 = fminf(fmaxf(rintf(v.y / scale), -QMAXF), QMAXF);
    float r2 = fminf(fmaxf(rintf(v.z / scale), -QMAXF), QMAXF);
    float r3 = fminf(fmaxf(rintf(v.w / scale), -QMAXF), QMAXF);
    words[g] = ((int)r0 & 255) | (((int)r1 & 255) << 8) |
               (((int)r2 & 255) << 16) | ((int)r3 << 24);
  }
  *(i32x4*)dst = *(const i32x4*)words;
}

// ---------------------------------------------------------------------------
// Kernel 3: i8 NT GEMM, 256x256 tile, depth-1 double buffer, 1 barrier/tile.
// 8 waves (2M x 4N), wave tile 128x64, K-tile = 128 B. LDS 128 KiB.
// All fragment ds_reads issued at tile start (plain loads -> compiler emits
// counted lgkmcnt at first use); full next-tile prefetch issued at tile start
// into the OTHER slot (lead = 1 tile >> HBM latency, so the single end-of-
// tile vmcnt(0) is free). MFMA quadrants overlap the LDS pipe instead of
// being barrier-serialized (round-3's 38% MfmaUtil == serialized model).
// Hazards: stages write slot d^1 only; t-1's reads of d^1 completed before
// its end barrier (consumed by its MFMAs); t+1 reads after vmcnt(0)+barrier.
// Swizzle: 16B-unit ^= (row>>1)&7 on pre-swizzled global source (linear LDS
// dest, rule #21) and on ds_read addresses (round-3: 0 bank conflicts).
// ---------------------------------------------------------------------------
__device__ __forceinline__ void load_half_a(i32x4 a[4][2], const char* p, int u0, int u1) {
#pragma unroll
  for (int f = 0; f < 4; ++f) {
    a[f][0] = *(const i32x4*)(p + f * 2048 + u0);
    a[f][1] = *(const i32x4*)(p + f * 2048 + u1);
  }
}
__device__ __forceinline__ void load_half_b(i32x4 b[2][2], const char* p, int u0, int u1) {
#pragma unroll
  for (int g = 0; g < 2; ++g) {
    b[g][0] = *(const i32x4*)(p + g * 2048 + u0);
    b[g][1] = *(const i32x4*)(p + g * 2048 + u1);
  }
}
template <int QA, int QB>
__device__ __forceinline__ void do_mfma(i32x4 acc[8][4], const i32x4 a[4][2],
                                        const i32x4 b[2][2]) {
#pragma unroll
  for (int f = 0; f < 4; ++f)
#pragma unroll
    for (int g = 0; g < 2; ++g) {
      i32x4 c = acc[QA * 4 + f][QB * 2 + g];
      c = __builtin_amdgcn_mfma_i32_16x16x64_i8(a[f][0], b[g][0], c, 0, 0, 0);
      c = __builtin_amdgcn_mfma_i32_16x16x64_i8(a[f][1], b[g][1], c, 0, 0, 0);
      acc[QA * 4 + f][QB * 2 + g] = c;
    }
}
__device__ __forceinline__ void stage2(const char* g0, long K, char* ld) {
  __builtin_amdgcn_global_load_lds((const AS1 void*)g0, (AS3 void*)ld, 16, 0, 0);
  __builtin_amdgcn_global_load_lds((const AS1 void*)(g0 + 64 * K), (AS3 void*)(ld + 8192), 16, 0, 0);
}

__global__ __launch_bounds__(512, 2) void gemm_k(
    const char* __restrict__ qx, const char* __restrict__ qw,
    const float* __restrict__ amax, const float* __restrict__ bias,
    float* __restrict__ out) {
  constexpr int K = 4096, N = 4096, NT = 32;  // NT = K / 128
  __shared__ __align__(16) char lds[131072];
  char* ldsA = lds;
  char* ldsB = lds + 65536;

  // XCD swizzle (512 blocks, %8==0 -> bijective). 32 M-tiles x 16 N-tiles.
  int cpx = (int)gridDim.x >> 3;
  int sw  = ((int)blockIdx.x & 7) * cpx + ((int)blockIdx.x >> 3);
  int tm = sw >> 4, tn = sw & 15;
  long brow = (long)tm * 256, bcol = (long)tn * 256;

  int tid = threadIdx.x;
  int l = tid & 63, wid = tid >> 6;
  int wr = wid >> 2, wc = wid & 3;  // 2 x 4 waves

  // ds-read per-lane offsets: phys unit = (logical) ^ ((row>>1)&7), row =
  // 16-aligned base + (l&15) -> swz term (l>>1)&7.
  int sl = (l >> 1) & 7;
  int u0 = (((l >> 4) ^ sl)) << 4;
  int u1 = ((((l >> 4) | 4) ^ sl)) << 4;
  int rA = (wr * 128 + (l & 15)) * 128;
  int rB = (wc * 64 + (l & 15)) * 128;

  // staging: thread covers row sr0 / sr0+64 per stage2, unit pre-swizzled in
  // the global source ((row>>1)&7 invariant under +64/+128).
  int sr0 = tid >> 3;
  int lu16 = ((tid & 7) ^ ((sr0 >> 1) & 7)) << 4;
  const char* gA = qx + (brow + sr0) * (long)K + lu16;
  const char* gB = qw + (bcol + sr0) * (long)K + lu16;

  i32x4 acc[8][4];
#pragma unroll
  for (int i = 0; i < 8; ++i)
#pragma unroll
    for (int j = 0; j < 4; ++j) acc[i][j] = 0;
  i32x4 a[4][2], b0[2][2], b1[2][2];

  // ---- prologue: full tile 0 into slot 0, drain, barrier.
  stage2(gA, K, ldsA + tid * 16);
  stage2(gA + 128 * (long)K, K, ldsA + 16384 + tid * 16);
  stage2(gB, K, ldsB + tid * 16);
  stage2(gB + 128 * (long)K, K, ldsB + 16384 + tid * 16);
  asm volatile("s_waitcnt vmcnt(0)" ::: "memory");
  __builtin_amdgcn_s_barrier();

  for (int t = 0; t < NT; ++t) {
    int d = t & 1;
    const char* cA = ldsA + d * 32768;
    const char* cB = ldsB + d * 32768;
    char* nA = ldsA + (d ^ 1) * 32768;
    char* nB = ldsB + (d ^ 1) * 32768;

    // issue fragment reads (a-low, both b halves) -- compiler schedules waits
    load_half_a(a, cA + rA, u0, u1);
    load_half_b(b0, cB + rB, u0, u1);
    load_half_b(b1, cB + rB + 4096, u0, u1);

    // prefetch next K-tile into the other slot (full-tile lead)
    if (t + 1 < NT) {
      const char* pA = gA + (t + 1) * 128;
      const char* pB = gB + (t + 1) * 128;
      stage2(pA, K, nA + tid * 16);
      stage2(pA + 128 * (long)K, K, nA + 16384 + tid * 16);
      stage2(pB, K, nB + tid * 16);
      stage2(pB + 128 * (long)K, K, nB + 16384 + tid * 16);
    }
    __builtin_amdgcn_sched_barrier(0);  // pin: all issues above the MFMA body

    __builtin_amdgcn_s_setprio(1);
    do_mfma<0, 0>(acc, a, b0);
    do_mfma<0, 1>(acc, a, b1);
    __builtin_amdgcn_s_setprio(0);

    load_half_a(a, cA + rA + 8192, u0, u1);  // a-high into the same regs

    __builtin_amdgcn_s_setprio(1);
    do_mfma<1, 1>(acc, a, b1);
    do_mfma<1, 0>(acc, a, b0);
    __builtin_amdgcn_s_setprio(0);

    asm volatile("s_waitcnt vmcnt(0)" ::: "memory");  // free: issued 1 tile ago
    __builtin_amdgcn_s_barrier();
  }

  // ---- epilogue: out = sx*sw*acc + bias (C/D: col=lane&15, row=(l>>4)*4+r)
  float ax = amax[(int)(brow >> 11)];
  float aw = amax[4];
  float scale = (fmaxf(ax, EPSF) / QMAXF) * (fmaxf(aw, EPSF) / QMAXF);
#pragma unroll
  for (int fb = 0; fb < 4; ++fb) {
    int col = (int)bcol + wc * 64 + fb * 16 + (l & 15);
    float bv = bias[col];
#pragma unroll
    for (int fa = 0; fa < 8; ++fa) {
      long r0 = brow + wr * 128 + fa * 16 + ((l >> 4) * 4);
#pragma unroll
      for (int r = 0; r < 4; ++r)
        out[(r0 + r) * N + col] = scale * (float)acc[fa][fb][r] + bv;
    }
  }
}

// ---------------------------------------------------------------------------
extern "C" void kernel_launch(void* const* d_in, const int* in_sizes, int n_in,
                              void* d_out, int out_size, void* d_ws, size_t ws_size,
                              hipStream_t stream) {
  const float* x    = (const float*)d_in[0];
  const float* w    = (const float*)d_in[1];
  const float* bias = (const float*)d_in[2];
  float* out = (float*)d_out;

  float* amax = (float*)d_ws;
  char* qx = (char*)d_ws + 256;
  char* qw = qx + XTOT;
  if (ws_size < (size_t)(256 + XTOT + WTOT)) return;

  hipMemsetAsync(d_ws, 0, 32, stream);

  amax_k<<<3072, 256, 0, stream>>>(x, w, amax);

  long total = XTOT + WTOT;
  int qblocks = (int)(total / 16 / 256);  // 12288
  quant_k<<<qblocks, 256, 0, stream>>>(x, w, amax, qx, qw);

  gemm_k<<<512, 512, 0, stream>>>(qx, qw, amax, bias, out);
}